// Round 5
// baseline (835.417 us; speedup 1.0000x reference)
//
#include <hip/hip_runtime.h>
#include <cstdint>
#include <cstddef>

// Problem dims
static constexpr int Mrows = 4096;   // B*N = 8*512
static constexpr int K1 = 4608;      // D_IN (== D_HID: both layers have K=4608)
static constexpr int N1 = 4608;      // D_HID
static constexpr int N2 = 1152;      // D_OUT
// prep_w2x uses 64x64 tiles: w1 -> 72x72 partials, w2 -> 72x18
static constexpr int NPART1 = (K1 / 64) * (N1 / 64);   // 5184
static constexpr int NPART2 = (K1 / 64) * (N2 / 64);   // 1296

typedef float  f32x4  __attribute__((ext_vector_type(4)));
typedef __bf16 bf16x8 __attribute__((ext_vector_type(8)));
typedef unsigned short u16x8 __attribute__((ext_vector_type(8)));

__device__ __forceinline__ unsigned short f2bf(float f) {
  unsigned int u = __float_as_uint(f);
  u += 0x7fffu + ((u >> 16) & 1u);           // RNE
  return (unsigned short)(u >> 16);
}
__device__ __forceinline__ float bf2f(unsigned short h) {
  return __uint_as_float(((unsigned int)h) << 16);
}
__device__ __forceinline__ float cleanf(float s) {
  if (__builtin_isnan(s)) return 1e-5f;
  if (__builtin_isinf(s)) return 1.0f;
  return s;
}

// ---------------------------------------------------------------------------
// prep_in: mu -> bf16 A1; sigma -> bf16 As16; row sums of mu^2, sigma
// ---------------------------------------------------------------------------
__global__ __launch_bounds__(256) void prep_in(
    const float* __restrict__ mu, const float* __restrict__ sg,
    unsigned short* __restrict__ A1, unsigned short* __restrict__ As16,
    float* __restrict__ rmu2, float* __restrict__ rsg)
{
  const int row = blockIdx.x;
  const int tid = threadIdx.x;
  const float4* mup = (const float4*)(mu + (size_t)row * K1);
  const float4* sgp = (const float4*)(sg + (size_t)row * K1);
  ushort4* a1p = (ushort4*)(A1 + (size_t)row * K1);
  ushort4* asp = (ushort4*)(As16 + (size_t)row * K1);
  float smu = 0.f, ssg = 0.f;
  for (int j = tid; j < K1 / 4; j += 256) {
    float4 m4 = mup[j];
    float4 s4 = sgp[j];
    smu += m4.x*m4.x + m4.y*m4.y + m4.z*m4.z + m4.w*m4.w;
    ssg += s4.x + s4.y + s4.z + s4.w;
    a1p[j] = make_ushort4(f2bf(m4.x), f2bf(m4.y), f2bf(m4.z), f2bf(m4.w));
    asp[j] = make_ushort4(f2bf(s4.x), f2bf(s4.y), f2bf(s4.z), f2bf(s4.w));
  }
  __shared__ float red[2][4];
  for (int off = 32; off; off >>= 1) {
    smu += __shfl_down(smu, off);
    ssg += __shfl_down(ssg, off);
  }
  const int lane = tid & 63, wv = tid >> 6;
  if (!lane) { red[0][wv] = smu; red[1][wv] = ssg; }
  __syncthreads();
  if (tid == 0) {
    rmu2[row] = red[0][0] + red[0][1] + red[0][2] + red[0][3];
    rsg[row]  = red[1][0] + red[1][1] + red[1][2] + red[1][3];
  }
}

// ---------------------------------------------------------------------------
// prep_w2x: BOTH weights in one launch. 64x64 tiles; float4 reads, LDS
// transpose ([64][65] floats, <=2-way conflicts), ushort8 16B stores of
// Bt[N][K] (bf16 w) and Bsq[N][K] (bf16 w^2). One f32 KL partial per block.
// grid = (K1/64, N1/64 + N2/64) = (72, 90).
// ---------------------------------------------------------------------------
__global__ __launch_bounds__(256) void prep_w2x(
    const float* __restrict__ w1, const float* __restrict__ w2,
    unsigned short* __restrict__ B1t, unsigned short* __restrict__ B1sq,
    unsigned short* __restrict__ B2t, unsigned short* __restrict__ B2sq,
    float* __restrict__ part1, float* __restrict__ part2)
{
  const int ybl = blockIdx.y;
  const bool is2 = ybl >= (N1 / 64);
  const int nb = is2 ? (ybl - N1 / 64) : ybl;
  const float* w = is2 ? w2 : w1;
  unsigned short* Bt = is2 ? B2t : B1t;
  unsigned short* Bq = is2 ? B2sq : B1sq;
  float* parts = is2 ? part2 : part1;
  const int N = is2 ? N2 : N1;

  const int kt = blockIdx.x * 64;
  const int nt = nb * 64;
  const int tid = threadIdx.x;

  __shared__ float t[64][65];
  float loc = 0.f;
  {
    const int r = tid >> 4;          // 0..15
    const int c = (tid & 15) * 4;    // 0..60
#pragma unroll
    for (int p = 0; p < 4; ++p) {
      const int k = p * 16 + r;
      float4 v = *(const float4*)(w + (size_t)(kt + k) * N + nt + c);
      t[k][c] = v.x; t[k][c + 1] = v.y; t[k][c + 2] = v.z; t[k][c + 3] = v.w;
      loc += v.x*v.x + v.y*v.y + v.z*v.z + v.w*v.w;
    }
  }
  __syncthreads();
  {
    const int kk = (tid & 7) * 8;    // 8 consecutive k per thread
#pragma unroll
    for (int q = 0; q < 2; ++q) {
      const int n = (tid >> 3) + q * 32;
      u16x8 bt, bq;
#pragma unroll
      for (int i = 0; i < 8; ++i) {
        float v = t[kk + i][n];
        bt[i] = f2bf(v);
        bq[i] = f2bf(v * v);
      }
      size_t o = (size_t)(nt + n) * K1 + (kt + kk);
      *(u16x8*)(Bt + o) = bt;
      *(u16x8*)(Bq + o) = bq;
    }
  }
  __shared__ float red[4];
  for (int off = 32; off; off >>= 1) loc += __shfl_down(loc, off);
  const int lane = tid & 63, wv = tid >> 6;
  if (!lane) red[wv] = loc;
  __syncthreads();
  if (tid == 0)
    parts[nb * (K1 / 64) + blockIdx.x] = red[0] + red[1] + red[2] + red[3];
}

// ---------------------------------------------------------------------------
// kl_prep: softplus vectors ws1/ws2, reduce prep_w partials, KL scalar
// ---------------------------------------------------------------------------
__global__ __launch_bounds__(256) void kl_prep(
    const float* __restrict__ wsig1, const float* __restrict__ wsig2,
    const float* __restrict__ part1, const float* __restrict__ part2,
    float* __restrict__ ws1, float* __restrict__ ws2, float* __restrict__ outkl)
{
  const int tid = threadIdx.x;
  float s1 = 0.f, l1 = 0.f, s2 = 0.f, l2 = 0.f, q1 = 0.f, q2 = 0.f;
  for (int j = tid; j < N1; j += 256) {
    float x = wsig1[j];
    float sp = (x > 20.f) ? x : log1pf(expf(x));
    ws1[j] = sp; s1 += sp; l1 += logf(sp);
  }
  for (int j = tid; j < N2; j += 256) {
    float x = wsig2[j];
    float sp = (x > 20.f) ? x : log1pf(expf(x));
    ws2[j] = sp; s2 += sp; l2 += logf(sp);
  }
  for (int j = tid; j < NPART1; j += 256) q1 += part1[j];
  for (int j = tid; j < NPART2; j += 256) q2 += part2[j];
  __shared__ float red[6][4];
  for (int off = 32; off; off >>= 1) {
    s1 += __shfl_down(s1, off); l1 += __shfl_down(l1, off);
    s2 += __shfl_down(s2, off); l2 += __shfl_down(l2, off);
    q1 += __shfl_down(q1, off); q2 += __shfl_down(q2, off);
  }
  const int lane = tid & 63, wv = tid >> 6;
  if (!lane) {
    red[0][wv] = s1; red[1][wv] = l1; red[2][wv] = s2;
    red[3][wv] = l2; red[4][wv] = q1; red[5][wv] = q2;
  }
  __syncthreads();
  if (tid == 0) {
    float S1v = red[0][0] + red[0][1] + red[0][2] + red[0][3];
    float L1v = red[1][0] + red[1][1] + red[1][2] + red[1][3];
    float S2v = red[2][0] + red[2][1] + red[2][2] + red[2][3];
    float L2v = red[3][0] + red[3][1] + red[3][2] + red[3][3];
    float Q1v = red[4][0] + red[4][1] + red[4][2] + red[4][3];
    float Q2v = red[5][0] + red[5][1] + red[5][2] + red[5][3];
    const float d = 4608.f;   // w_mu.shape[0] for BOTH layers
    float kl1 = 0.5f * (d * (S1v / (float)N1) + Q1v / (float)N1 - d - d * (L1v / (float)N1));
    float kl2 = 0.5f * (d * (S2v / (float)N2) + Q2v / (float)N2 - d - d * (L2v / (float)N2));
    outkl[0] = kl1 + kl2;
  }
}

#define GLD16(gp, lp) __builtin_amdgcn_global_load_lds( \
    (__attribute__((address_space(1))) void*)(unsigned short*)(gp), \
    (__attribute__((address_space(3))) void*)(lp), 16, 0, 0)

__device__ __forceinline__ void storeC(float v, float* p) { *p = v; }
__device__ __forceinline__ void storeC(float v, unsigned short* p) { *p = f2bf(v); }

// ---------------------------------------------------------------------------
// gemm256<NT, CT, FUSE>: dual GEMM (z=0 mu, z=1 sigma), A/B bf16, K = 4608.
// 256x192 tile, BK=64, 512 threads (8 waves 2Mx4N, 128x48 per wave).
// Layer 1 (FUSE=0): NT=4608, C bf16; grid 24x16x2 = 768 = 3x256.
// Layer 2 (FUSE=1): NT=1152, C f32 = final outputs; grid 6x16x2 = 192.
//
// LDS: lA [2][256][128B] = 65536, lB [2][192][128B] = 49152 (114688 total)
// Swizzle: LDS slot s of a row holds GLOBAL granule (s ^ (row&7)); written by
// pre-swizzling the global source (linear LDS dest), read with same XOR ->
// ds_read_b128 conflict-free (measured 0).
//
// K-loop (R5): 2 barriers + 1 lgkm drain per K-tile (was 6 barriers + 2
// drains in 3 phases; measured ~1280 cyc/K-tile of stall). Within a K-tile
// all 22 frag reads target the stable 'cur' buffer -> inter-phase barriers
// had no hazard to protect. Real hazards:
//   entry-bar: staging of cur landed (vmcnt at end of prev iter) AND alt
//              fully consumed (waves passed prev iter's reads).
//   mid-bar:   all waves' B-frag reads done before stB overwrites cur's B.
// Schedule per iter t (cur = t&1):
//   entry-bar -> issue 22 ds_read (B then A) -> stA(alt)x2 ->
//   lgkmcnt(0) + sched_barrier (rule #18) -> mid-bar -> stB(cur,t+2) ->
//   48 MFMA under setprio -> vmcnt(3) [tail: vmcnt(0)] -> end-bar
// vmcnt(3) leaves only B(t+2) in flight => A(t+1), B(t+1) resident at the
// next entry-bar (same bookkeeping as R2-R4, verified).
// ---------------------------------------------------------------------------
template <int NT, typename CT, bool FUSE>
__global__ __launch_bounds__(512, 2) void gemm256(
    const unsigned short* __restrict__ Amu, const unsigned short* __restrict__ Asg,
    const unsigned short* __restrict__ Bmu, const unsigned short* __restrict__ Bsq,
    CT* __restrict__ Cmu, CT* __restrict__ Csg,
    const int* __restrict__ mask2, const float* __restrict__ ws2,
    const float* __restrict__ r2mu, const float* __restrict__ r2sg)
{
  __shared__ __align__(16) char smem[114688];
  char* lA = smem;             // [2][256][128B] = 65536
  char* lB = smem + 65536;     // [2][192][128B] = 49152

  const int tid  = threadIdx.x;
  const int lane = tid & 63;
  const int wave = tid >> 6;
  const int which = blockIdx.z;
  const unsigned short* Ag = which ? Asg : Amu;
  const unsigned short* Bg = which ? Bsq : Bmu;
  CT* Cg = which ? Csg : Cmu;

  const int m0 = blockIdx.y * 256;
  const int n0 = blockIdx.x * 192;
  const int wm = (wave >> 2) * 128;       // 0 / 128
  const int wn = (wave & 3) * 48;         // 0 / 48 / 96 / 144
  const int fm = lane & 15;
  const int kq = lane >> 4;               // 0..3

  // staging geometry: thread covers (row = base + tid>>3, slot tid&7);
  // global granule = slot ^ (row&7); row&7 == (tid>>3)&7 for every 64-row chunk
  const int rbase = tid >> 3;             // 0..63
  const int gg = (tid & 7) ^ (rbase & 7);
  const unsigned short* gA0 = Ag + (size_t)(m0 + rbase) * K1 + gg * 8;
  const unsigned short* gB0 = Bg + (size_t)(n0 + rbase) * K1 + gg * 8;

  auto stA = [&](int buf, int h, int kt2) {        // half h = 128 rows, 2 loads
    const unsigned short* g = gA0 + (size_t)h * 128 * K1 + (size_t)kt2 * 64;
    char* l = lA + buf * 32768 + h * 16384 + tid * 16;
    GLD16(g, l);
    GLD16(g + (size_t)64 * K1, l + 8192);
  };
  auto stB = [&](int buf, int kt2) {               // all 192 rows, 3 loads
    const unsigned short* g = gB0 + (size_t)kt2 * 64;
    char* l = lB + buf * 24576 + tid * 16;
    GLD16(g, l);
    GLD16(g + (size_t)64 * K1, l + 8192);
    GLD16(g + (size_t)128 * K1, l + 16384);
  };

  // frag read bases (byte offsets)
  const int abase = (wm + fm) * 128;               // within lA buf
  const int bbase = 65536 + (wn + fm) * 128;       // within smem (lB region)
  const int x0 = ((0 * 4 + kq) ^ (fm & 7)) * 16;   // ksub 0 granule (swizzled)
  const int x1 = ((1 * 4 + kq) ^ (fm & 7)) * 16;   // ksub 1 granule

  f32x4 acc[8][3];
#pragma unroll
  for (int i = 0; i < 8; ++i)
#pragma unroll
    for (int j = 0; j < 3; ++j) acc[i][j] = (f32x4){0.f, 0.f, 0.f, 0.f};

  // prologue: B(0), A(0) -> buf0; B(1) -> buf1; wait tile-0 loads (leave B(1))
  stB(0, 0);
  stA(0, 0, 0); stA(0, 1, 0);
  stB(1, 1);
  asm volatile("s_waitcnt vmcnt(3)" ::: "memory");
  __builtin_amdgcn_s_barrier();

  const int ksteps = K1 / 64;   // 72
  for (int kt = 0; kt < ksteps; ++kt) {
    const int cur = kt & 1;
    const char* cA = lA + cur * 32768 + abase;
    const char* cB = smem + cur * 24576 + bbase;

    bf16x8 Af[8][2], Bf[3][2];

    // issue ALL frag reads for this K-tile (cur buffer is stable throughout)
#pragma unroll
    for (int j = 0; j < 3; ++j) {
      Bf[j][0] = *(const bf16x8*)(cB + j * 2048 + x0);
      Bf[j][1] = *(const bf16x8*)(cB + j * 2048 + x1);
    }
#pragma unroll
    for (int i = 0; i < 8; ++i) {
      Af[i][0] = *(const bf16x8*)(cA + i * 2048 + x0);
      Af[i][1] = *(const bf16x8*)(cA + i * 2048 + x1);
    }
    // stage next A-tile into alt (alt fully consumed before this iter's entry)
    if (kt + 1 < ksteps) { stA(cur ^ 1, 0, kt + 1); stA(cur ^ 1, 1, kt + 1); }

    asm volatile("s_waitcnt lgkmcnt(0)" ::: "memory");
    __builtin_amdgcn_sched_barrier(0);       // rule #18: pin MFMA after drain
    __builtin_amdgcn_s_barrier();            // mid-bar: all waves' reads done

    // safe now: every wave finished its B-frag reads of cur
    if (kt + 2 < ksteps) stB(cur, kt + 2);

    __builtin_amdgcn_s_setprio(1);
#pragma unroll
    for (int i = 0; i < 8; ++i)
#pragma unroll
      for (int j = 0; j < 3; ++j) {
        acc[i][j] = __builtin_amdgcn_mfma_f32_16x16x32_bf16(Af[i][0], Bf[j][0], acc[i][j], 0, 0, 0);
        acc[i][j] = __builtin_amdgcn_mfma_f32_16x16x32_bf16(Af[i][1], Bf[j][1], acc[i][j], 0, 0, 0);
      }
    __builtin_amdgcn_s_setprio(0);

    if (kt < ksteps - 2) asm volatile("s_waitcnt vmcnt(3)" ::: "memory");
    else                 asm volatile("s_waitcnt vmcnt(0)" ::: "memory");
    __builtin_amdgcn_s_barrier();            // end-bar (= next entry-bar)
  }

  // epilogue: C[16x16] frag layout col=lane&15, row=(lane>>4)*4+r
  const int rr = (lane >> 4) * 4;
  const int cc = lane & 15;
  if constexpr (!FUSE) {
#pragma unroll
    for (int i = 0; i < 8; ++i) {
      const int grow = m0 + wm + i * 16 + rr;
#pragma unroll
      for (int j = 0; j < 3; ++j) {
        const int gcol = n0 + wn + j * 16 + cc;
        CT* cp = Cg + (size_t)grow * NT + gcol;
#pragma unroll
        for (int r = 0; r < 4; ++r) storeC(acc[i][j][r], cp + (size_t)r * NT);
      }
    }
  } else {
    // layer-2 tail fused: z=0 -> out_mu (dropout only); z=1 -> out_sig
    const float inv_keep  = 1.f / 0.9f;
    const float inv_units = 1.f / 1152.f;
    float wcol[3];
    if (which) {
#pragma unroll
      for (int j = 0; j < 3; ++j) wcol[j] = ws2[n0 + wn + j * 16 + cc];
    }
#pragma unroll
    for (int i = 0; i < 8; ++i) {
#pragma unroll
      for (int r = 0; r < 4; ++r) {
        const int grow = m0 + wm + i * 16 + rr + r;
        const float rterm = which ? (r2mu[grow] + r2sg[grow]) : 0.f;
#pragma unroll
        for (int j = 0; j < 3; ++j) {
          const int gcol = n0 + wn + j * 16 + cc;
          const float mm = (float)mask2[(size_t)grow * NT + gcol];
          const float v = acc[i][j][r];
          float o;
          if (which == 0) {
            o = v * mm * inv_keep;
          } else {
            float sig4 = cleanf(v + rterm * wcol[j]);
            o = cleanf(cleanf(sig4 * mm * inv_units));
          }
          Cg[(size_t)grow * NT + gcol] = (CT)o;
        }
      }
    }
  }
}

// ---------------------------------------------------------------------------
// mid: layer-1 epilogue: sigma assembly, GELU moments, dropout;
// emits A2 bf16 + As2 bf16; row sums for layer-2 Sigma terms.
// ---------------------------------------------------------------------------
__global__ __launch_bounds__(256) void mid_kernel(
    const unsigned short* __restrict__ mu1, const unsigned short* __restrict__ S1,
    const int* __restrict__ mask1, const float* __restrict__ ws1,
    const float* __restrict__ rmu2, const float* __restrict__ rsg,
    unsigned short* __restrict__ A2, unsigned short* __restrict__ As2,
    float* __restrict__ r2mu, float* __restrict__ r2sg)
{
  const int row = blockIdx.x;
  const int tid = threadIdx.x;
  const float rterm = rmu2[row] + rsg[row];
  const ushort4* mup = (const ushort4*)(mu1 + (size_t)row * N1);
  const ushort4* s1p = (const ushort4*)(S1 + (size_t)row * N1);
  const int4* mkp = (const int4*)(mask1 + (size_t)row * N1);
  const float4* wsp = (const float4*)ws1;
  ushort4* a2p = (ushort4*)(A2 + (size_t)row * N1);
  ushort4* as2p = (ushort4*)(As2 + (size_t)row * N1);
  float smu = 0.f, ssg = 0.f;
  for (int j = tid; j < N1 / 4; j += 256) {
    ushort4 m4 = mup[j]; ushort4 s4 = s1p[j]; int4 k4 = mkp[j]; float4 w4 = wsp[j];
    float xv[4] = {bf2f(m4.x), bf2f(m4.y), bf2f(m4.z), bf2f(m4.w)};
    float Sv[4] = {bf2f(s4.x), bf2f(s4.y), bf2f(s4.z), bf2f(s4.w)};
    float wv[4] = {w4.x, w4.y, w4.z, w4.w};
    int   kv[4] = {k4.x, k4.y, k4.z, k4.w};
    unsigned short oa[4], os[4];
#pragma unroll
    for (int t = 0; t < 4; t++) {
      float sig1 = cleanf(Sv[t] + rterm * wv[t]);
      float x = xv[t];
      float cdf = 0.5f * (1.f + erff(x * 0.70710678118654752f));
      float pdf = expf(-0.5f * x * x) * 0.3989422804014327f;
      float g = cdf + x * pdf;
      float mu2v = x * cdf;
      float sig2 = g * g * sig1;
      float mm = (float)kv[t];
      float mu3 = mu2v * mm * (1.f / 0.9f);
      float sig3 = cleanf(sig2 * mm * (1.f / 4608.f));
      smu += mu3 * mu3;
      ssg += sig3;
      oa[t] = f2bf(mu3);
      os[t] = f2bf(sig3);
    }
    a2p[j] = make_ushort4(oa[0], oa[1], oa[2], oa[3]);
    as2p[j] = make_ushort4(os[0], os[1], os[2], os[3]);
  }
  __shared__ float red[2][4];
  for (int off = 32; off; off >>= 1) {
    smu += __shfl_down(smu, off);
    ssg += __shfl_down(ssg, off);
  }
  const int lane = tid & 63, wv2 = tid >> 6;
  if (!lane) { red[0][wv2] = smu; red[1][wv2] = ssg; }
  __syncthreads();
  if (tid == 0) {
    r2mu[row] = red[0][0] + red[0][1] + red[0][2] + red[0][3];
    r2sg[row] = red[1][0] + red[1][1] + red[1][2] + red[1][3];
  }
}

// ---------------------------------------------------------------------------
extern "C" void kernel_launch(void* const* d_in, const int* in_sizes, int n_in,
                              void* d_out, int out_size, void* d_ws, size_t ws_size,
                              hipStream_t stream)
{
  const float* mu_in = (const float*)d_in[0];
  const float* sg_in = (const float*)d_in[1];
  const int* mask1 = (const int*)d_in[2];
  const int* mask2 = (const int*)d_in[3];
  const float* w_mu1 = (const float*)d_in[4];
  const float* wsig1 = (const float*)d_in[5];
  const float* w_mu2 = (const float*)d_in[6];
  const float* wsig2 = (const float*)d_in[7];
  float* out = (float*)d_out;

  char* ws = (char*)d_ws;
  // Fixed layout with explicit overlays (bytes):
  const size_t oA1  = 0;                           // 37,748,736  A1 / A2 (bf16)
  const size_t oAs  = oA1  + (size_t)37748736;     // As16 (L1/L2 sigma, bf16)
  const size_t oB1t = oAs  + (size_t)37748736;     // 42,467,328  B1t
  const size_t oB1q = oB1t + (size_t)42467328;     // B1sq16
  const size_t oB2t = oB1q + (size_t)42467328;     // 10,616,832
  const size_t oB2q = oB2t + (size_t)10616832;     // B2sq16
  const size_t oMu1 = oB2q + (size_t)10616832;     // 37,748,736  mu1b
  const size_t oS1  = oMu1 + (size_t)37748736;     // S1b16
  const size_t oVec = oS1  + (size_t)37748736;

  unsigned short* A1     = (unsigned short*)(ws + oA1);
  unsigned short* As16   = (unsigned short*)(ws + oAs);   // sigma activations (bf16)
  unsigned short* B1t    = (unsigned short*)(ws + oB1t);
  unsigned short* B1sq16 = (unsigned short*)(ws + oB1q);
  unsigned short* B2t    = (unsigned short*)(ws + oB2t);
  unsigned short* B2sq16 = (unsigned short*)(ws + oB2q);
  unsigned short* mu1b   = (unsigned short*)(ws + oMu1);
  unsigned short* S1b16  = (unsigned short*)(ws + oS1);

  float* rmu2 = (float*)(ws + oVec);
  float* rsg  = rmu2 + Mrows;
  float* r2mu = rsg + Mrows;
  float* r2sg = r2mu + Mrows;
  float* ws1v = r2sg + Mrows;
  float* ws2v = ws1v + N1;
  float* part1 = ws2v + N2;            // NPART1 floats
  float* part2 = part1 + NPART1;       // NPART2 floats

  prep_in<<<Mrows, 256, 0, stream>>>(mu_in, sg_in, A1, As16, rmu2, rsg);
  prep_w2x<<<dim3(K1 / 64, N1 / 64 + N2 / 64), 256, 0, stream>>>(
      w_mu1, w_mu2, B1t, B1sq16, B2t, B2sq16, part1, part2);
  kl_prep<<<1, 256, 0, stream>>>(wsig1, wsig2, part1, part2, ws1v, ws2v,
                                 out + (size_t)2 * Mrows * N2);

  // layer 1: mu + sigma (both bf16) z-packed; 24 x 16 x 2 = 768 = 3 x 256
  gemm256<N1, unsigned short, false><<<dim3(N1 / 192, Mrows / 256, 2), 512, 0, stream>>>(
      A1, As16, B1t, B1sq16, mu1b, S1b16, nullptr, nullptr, nullptr, nullptr);

  mid_kernel<<<Mrows, 256, 0, stream>>>(mu1b, S1b16, mask1, ws1v, rmu2, rsg,
                                        A1, As16, r2mu, r2sg);

  // layer 2: same structure, NT=1152, fused final epilogue -> writes outputs
  gemm256<N2, float, true><<<dim3(N2 / 192, Mrows / 256, 2), 512, 0, stream>>>(
      A1, As16, B2t, B2sq16, out, out + (size_t)Mrows * N2,
      mask2, ws2v, r2mu, r2sg);

  (void)in_sizes; (void)n_in; (void)out_size; (void)ws_size;
}

// Round 6
// 793.611 us; speedup vs baseline: 1.0527x; 1.0527x over previous
//
#include <hip/hip_runtime.h>
#include <cstdint>
#include <cstddef>

// Problem dims
static constexpr int Mrows = 4096;   // B*N = 8*512
static constexpr int K1 = 4608;      // D_IN (== D_HID: both layers have K=4608)
static constexpr int N1 = 4608;      // D_HID
static constexpr int N2 = 1152;      // D_OUT
// prep_w2x uses 64x64 tiles: w1 -> 72x72 partials, w2 -> 72x18
static constexpr int NPART1 = (K1 / 64) * (N1 / 64);   // 5184
static constexpr int NPART2 = (K1 / 64) * (N2 / 64);   // 1296

typedef float  f32x4  __attribute__((ext_vector_type(4)));
typedef __bf16 bf16x8 __attribute__((ext_vector_type(8)));
typedef unsigned short u16x8 __attribute__((ext_vector_type(8)));

__device__ __forceinline__ unsigned short f2bf(float f) {
  unsigned int u = __float_as_uint(f);
  u += 0x7fffu + ((u >> 16) & 1u);           // RNE
  return (unsigned short)(u >> 16);
}
__device__ __forceinline__ float bf2f(unsigned short h) {
  return __uint_as_float(((unsigned int)h) << 16);
}
__device__ __forceinline__ float cleanf(float s) {
  if (__builtin_isnan(s)) return 1e-5f;
  if (__builtin_isinf(s)) return 1.0f;
  return s;
}

// ---------------------------------------------------------------------------
// prep_in: mu -> bf16 A1; sigma -> bf16 As16; row sums of mu^2, sigma
// ---------------------------------------------------------------------------
__global__ __launch_bounds__(256) void prep_in(
    const float* __restrict__ mu, const float* __restrict__ sg,
    unsigned short* __restrict__ A1, unsigned short* __restrict__ As16,
    float* __restrict__ rmu2, float* __restrict__ rsg)
{
  const int row = blockIdx.x;
  const int tid = threadIdx.x;
  const float4* mup = (const float4*)(mu + (size_t)row * K1);
  const float4* sgp = (const float4*)(sg + (size_t)row * K1);
  ushort4* a1p = (ushort4*)(A1 + (size_t)row * K1);
  ushort4* asp = (ushort4*)(As16 + (size_t)row * K1);
  float smu = 0.f, ssg = 0.f;
  for (int j = tid; j < K1 / 4; j += 256) {
    float4 m4 = mup[j];
    float4 s4 = sgp[j];
    smu += m4.x*m4.x + m4.y*m4.y + m4.z*m4.z + m4.w*m4.w;
    ssg += s4.x + s4.y + s4.z + s4.w;
    a1p[j] = make_ushort4(f2bf(m4.x), f2bf(m4.y), f2bf(m4.z), f2bf(m4.w));
    asp[j] = make_ushort4(f2bf(s4.x), f2bf(s4.y), f2bf(s4.z), f2bf(s4.w));
  }
  __shared__ float red[2][4];
  for (int off = 32; off; off >>= 1) {
    smu += __shfl_down(smu, off);
    ssg += __shfl_down(ssg, off);
  }
  const int lane = tid & 63, wv = tid >> 6;
  if (!lane) { red[0][wv] = smu; red[1][wv] = ssg; }
  __syncthreads();
  if (tid == 0) {
    rmu2[row] = red[0][0] + red[0][1] + red[0][2] + red[0][3];
    rsg[row]  = red[1][0] + red[1][1] + red[1][2] + red[1][3];
  }
}

// ---------------------------------------------------------------------------
// prep_w2x: BOTH weights in one launch. 64x64 tiles; float4 reads, LDS
// transpose ([64][65] floats, <=2-way conflicts), ushort8 16B stores of
// Bt[N][K] (bf16 w) and Bsq[N][K] (bf16 w^2). One f32 KL partial per block.
// grid = (K1/64, N1/64 + N2/64) = (72, 90).
// ---------------------------------------------------------------------------
__global__ __launch_bounds__(256) void prep_w2x(
    const float* __restrict__ w1, const float* __restrict__ w2,
    unsigned short* __restrict__ B1t, unsigned short* __restrict__ B1sq,
    unsigned short* __restrict__ B2t, unsigned short* __restrict__ B2sq,
    float* __restrict__ part1, float* __restrict__ part2)
{
  const int ybl = blockIdx.y;
  const bool is2 = ybl >= (N1 / 64);
  const int nb = is2 ? (ybl - N1 / 64) : ybl;
  const float* w = is2 ? w2 : w1;
  unsigned short* Bt = is2 ? B2t : B1t;
  unsigned short* Bq = is2 ? B2sq : B1sq;
  float* parts = is2 ? part2 : part1;
  const int N = is2 ? N2 : N1;

  const int kt = blockIdx.x * 64;
  const int nt = nb * 64;
  const int tid = threadIdx.x;

  __shared__ float t[64][65];
  float loc = 0.f;
  {
    const int r = tid >> 4;          // 0..15
    const int c = (tid & 15) * 4;    // 0..60
#pragma unroll
    for (int p = 0; p < 4; ++p) {
      const int k = p * 16 + r;
      float4 v = *(const float4*)(w + (size_t)(kt + k) * N + nt + c);
      t[k][c] = v.x; t[k][c + 1] = v.y; t[k][c + 2] = v.z; t[k][c + 3] = v.w;
      loc += v.x*v.x + v.y*v.y + v.z*v.z + v.w*v.w;
    }
  }
  __syncthreads();
  {
    const int kk = (tid & 7) * 8;    // 8 consecutive k per thread
#pragma unroll
    for (int q = 0; q < 2; ++q) {
      const int n = (tid >> 3) + q * 32;
      u16x8 bt, bq;
#pragma unroll
      for (int i = 0; i < 8; ++i) {
        float v = t[kk + i][n];
        bt[i] = f2bf(v);
        bq[i] = f2bf(v * v);
      }
      size_t o = (size_t)(nt + n) * K1 + (kt + kk);
      *(u16x8*)(Bt + o) = bt;
      *(u16x8*)(Bq + o) = bq;
    }
  }
  __shared__ float red[4];
  for (int off = 32; off; off >>= 1) loc += __shfl_down(loc, off);
  const int lane = tid & 63, wv = tid >> 6;
  if (!lane) red[wv] = loc;
  __syncthreads();
  if (tid == 0)
    parts[nb * (K1 / 64) + blockIdx.x] = red[0] + red[1] + red[2] + red[3];
}

// ---------------------------------------------------------------------------
// kl_prep: softplus vectors ws1/ws2, reduce prep_w partials, KL scalar
// ---------------------------------------------------------------------------
__global__ __launch_bounds__(256) void kl_prep(
    const float* __restrict__ wsig1, const float* __restrict__ wsig2,
    const float* __restrict__ part1, const float* __restrict__ part2,
    float* __restrict__ ws1, float* __restrict__ ws2, float* __restrict__ outkl)
{
  const int tid = threadIdx.x;
  float s1 = 0.f, l1 = 0.f, s2 = 0.f, l2 = 0.f, q1 = 0.f, q2 = 0.f;
  for (int j = tid; j < N1; j += 256) {
    float x = wsig1[j];
    float sp = (x > 20.f) ? x : log1pf(expf(x));
    ws1[j] = sp; s1 += sp; l1 += logf(sp);
  }
  for (int j = tid; j < N2; j += 256) {
    float x = wsig2[j];
    float sp = (x > 20.f) ? x : log1pf(expf(x));
    ws2[j] = sp; s2 += sp; l2 += logf(sp);
  }
  for (int j = tid; j < NPART1; j += 256) q1 += part1[j];
  for (int j = tid; j < NPART2; j += 256) q2 += part2[j];
  __shared__ float red[6][4];
  for (int off = 32; off; off >>= 1) {
    s1 += __shfl_down(s1, off); l1 += __shfl_down(l1, off);
    s2 += __shfl_down(s2, off); l2 += __shfl_down(l2, off);
    q1 += __shfl_down(q1, off); q2 += __shfl_down(q2, off);
  }
  const int lane = tid & 63, wv = tid >> 6;
  if (!lane) {
    red[0][wv] = s1; red[1][wv] = l1; red[2][wv] = s2;
    red[3][wv] = l2; red[4][wv] = q1; red[5][wv] = q2;
  }
  __syncthreads();
  if (tid == 0) {
    float S1v = red[0][0] + red[0][1] + red[0][2] + red[0][3];
    float L1v = red[1][0] + red[1][1] + red[1][2] + red[1][3];
    float S2v = red[2][0] + red[2][1] + red[2][2] + red[2][3];
    float L2v = red[3][0] + red[3][1] + red[3][2] + red[3][3];
    float Q1v = red[4][0] + red[4][1] + red[4][2] + red[4][3];
    float Q2v = red[5][0] + red[5][1] + red[5][2] + red[5][3];
    const float d = 4608.f;   // w_mu.shape[0] for BOTH layers
    float kl1 = 0.5f * (d * (S1v / (float)N1) + Q1v / (float)N1 - d - d * (L1v / (float)N1));
    float kl2 = 0.5f * (d * (S2v / (float)N2) + Q2v / (float)N2 - d - d * (L2v / (float)N2));
    outkl[0] = kl1 + kl2;
  }
}

#define GLD16(gp, lp) __builtin_amdgcn_global_load_lds( \
    (__attribute__((address_space(1))) void*)(unsigned short*)(gp), \
    (__attribute__((address_space(3))) void*)(lp), 16, 0, 0)

__device__ __forceinline__ void storeC(float v, float* p) { *p = v; }
__device__ __forceinline__ void storeC(float v, unsigned short* p) { *p = f2bf(v); }

// ---------------------------------------------------------------------------
// gemm256<NT, CT, FUSE>: dual GEMM (z=0 mu, z=1 sigma), A/B bf16, K = 4608.
// R6: 128x192 tile, BK=64, 512 threads (8 waves 2Mx4N, 64x48 per wave),
// LDS = 81,920 B exactly -> TWO blocks co-resident per CU (2 x 81,920 =
// 163,840 = full 160 KiB). The two blocks have independent barrier groups,
// so one block's MFMA fills the other's read/barrier stalls (the mechanism
// missing at 1 block/CU where all 8 waves drain together at each barrier).
// __launch_bounds__(512,4): 4 waves/SIMD -> VGPR capped at 128 (acc is now
// 48 VGPR, fits).
// Layer 1: grid 24x32x2 = 1536 = 3 x 512 slots (no tail).
// Layer 2: grid  6x32x2 =  384 <= 512 (fully co-resident), FUSE epilogue.
//
// LDS: lA [2][128][128B] = 32768, lB [2][192][128B] = 49152 (81920 total)
// Swizzle: LDS slot s of a row holds GLOBAL granule (s ^ (row&7)); written by
// pre-swizzling the global source (linear LDS dest), read with same XOR ->
// ds_read_b128 conflict-free (measured 0 since R1).
//
// 3 phases per K-tile (R4 schedule, proven faster than R5's 1-drain), 8 MFMA
// each:
//   ph0: read B cols{0,1,2} (6 b128) + A rows{0,1} (4); stage A(t+1).p0 -> alt
//        MFMA rows0-1 x cols0-1
//   ph1: read A rows{2,3} (4);                          stage A(t+1).p1 -> alt
//        MFMA rows2-3 x cols0-1
//   ph2: no ds_reads;  stage B(t+2) (3 loads) -> cur;   MFMA rows0-3 x col2
//        vmcnt(3) [tail: vmcnt(0)]
// vmcnt(3) leaves only B(t+2) in flight => A(t+1), B(t+1) resident (5 staging
// loads/iter: 1+1+3; same bookkeeping shape as R2-R4, re-verified).
// ---------------------------------------------------------------------------
template <int NT, typename CT, bool FUSE>
__global__ __launch_bounds__(512, 4) void gemm256(
    const unsigned short* __restrict__ Amu, const unsigned short* __restrict__ Asg,
    const unsigned short* __restrict__ Bmu, const unsigned short* __restrict__ Bsq,
    CT* __restrict__ Cmu, CT* __restrict__ Csg,
    const int* __restrict__ mask2, const float* __restrict__ ws2,
    const float* __restrict__ r2mu, const float* __restrict__ r2sg)
{
  __shared__ __align__(16) char smem[81920];
  char* lA = smem;             // [2][128][128B] = 32768
  // lB region: smem + 32768, [2][192][128B] = 49152

  const int tid  = threadIdx.x;
  const int lane = tid & 63;
  const int wave = tid >> 6;
  const int which = blockIdx.z;
  const unsigned short* Ag = which ? Asg : Amu;
  const unsigned short* Bg = which ? Bsq : Bmu;
  CT* Cg = which ? Csg : Cmu;

  const int m0 = blockIdx.y * 128;
  const int n0 = blockIdx.x * 192;
  const int wm = (wave >> 2) * 64;        // 0 / 64
  const int wn = (wave & 3) * 48;         // 0 / 48 / 96 / 144
  const int fm = lane & 15;
  const int kq = lane >> 4;               // 0..3

  // staging geometry: thread covers (row = base + tid>>3, slot tid&7);
  // global granule = slot ^ (row&7); row&7 == (tid>>3)&7 for every 64-row chunk
  const int rbase = tid >> 3;             // 0..63
  const int gg = (tid & 7) ^ (rbase & 7);
  const unsigned short* gA0 = Ag + (size_t)(m0 + rbase) * K1 + gg * 8;
  const unsigned short* gB0 = Bg + (size_t)(n0 + rbase) * K1 + gg * 8;

  auto stA = [&](int buf, int part, int kt2) {     // part = 64-row chunk, 1 load
    const unsigned short* g = gA0 + (size_t)part * 64 * K1 + (size_t)kt2 * 64;
    char* l = lA + buf * 16384 + part * 8192 + tid * 16;
    GLD16(g, l);
  };
  auto stB = [&](int buf, int kt2) {               // all 192 rows, 3 loads
    const unsigned short* g = gB0 + (size_t)kt2 * 64;
    char* l = smem + 32768 + buf * 24576 + tid * 16;
    GLD16(g, l);
    GLD16(g + (size_t)64 * K1, l + 8192);
    GLD16(g + (size_t)128 * K1, l + 16384);
  };

  // frag read bases (byte offsets)
  const int abase = (wm + fm) * 128;               // within lA buf
  const int bbase = 32768 + (wn + fm) * 128;       // within smem (lB region)
  const int x0 = ((0 * 4 + kq) ^ (fm & 7)) * 16;   // ksub 0 granule (swizzled)
  const int x1 = ((1 * 4 + kq) ^ (fm & 7)) * 16;   // ksub 1 granule

  f32x4 acc[4][3];
#pragma unroll
  for (int i = 0; i < 4; ++i)
#pragma unroll
    for (int j = 0; j < 3; ++j) acc[i][j] = (f32x4){0.f, 0.f, 0.f, 0.f};

  // prologue: B(0), A(0) -> buf0; B(1) -> buf1; wait tile-0 loads (leave B(1))
  stB(0, 0);
  stA(0, 0, 0); stA(0, 1, 0);
  stB(1, 1);
  asm volatile("s_waitcnt vmcnt(3)" ::: "memory");
  __builtin_amdgcn_s_barrier();

  const int ksteps = K1 / 64;   // 72
  for (int kt = 0; kt < ksteps; ++kt) {
    const int cur = kt & 1;
    const char* cA = lA + cur * 16384 + abase;
    const char* cB = smem + cur * 24576 + bbase;

    bf16x8 Af[4][2], Bf[3][2];

    // ---- phase 0: rows 0-1 x cols 0-1 ----
#pragma unroll
    for (int j = 0; j < 3; ++j) {
      Bf[j][0] = *(const bf16x8*)(cB + j * 2048 + x0);
      Bf[j][1] = *(const bf16x8*)(cB + j * 2048 + x1);
    }
#pragma unroll
    for (int i = 0; i < 2; ++i) {
      Af[i][0] = *(const bf16x8*)(cA + i * 2048 + x0);
      Af[i][1] = *(const bf16x8*)(cA + i * 2048 + x1);
    }
    if (kt + 1 < ksteps) stA(cur ^ 1, 0, kt + 1);
    asm volatile("s_waitcnt lgkmcnt(4)" ::: "memory");   // pace the 10 reads
    __builtin_amdgcn_s_barrier();
    asm volatile("s_waitcnt lgkmcnt(0)" ::: "memory");
    __builtin_amdgcn_s_setprio(1);
#pragma unroll
    for (int i = 0; i < 2; ++i)
#pragma unroll
      for (int j = 0; j < 2; ++j) {
        acc[i][j] = __builtin_amdgcn_mfma_f32_16x16x32_bf16(Af[i][0], Bf[j][0], acc[i][j], 0, 0, 0);
        acc[i][j] = __builtin_amdgcn_mfma_f32_16x16x32_bf16(Af[i][1], Bf[j][1], acc[i][j], 0, 0, 0);
      }
    __builtin_amdgcn_s_setprio(0);
    __builtin_amdgcn_s_barrier();

    // ---- phase 1: rows 2-3 x cols 0-1 ----
#pragma unroll
    for (int i = 2; i < 4; ++i) {
      Af[i][0] = *(const bf16x8*)(cA + i * 2048 + x0);
      Af[i][1] = *(const bf16x8*)(cA + i * 2048 + x1);
    }
    if (kt + 1 < ksteps) stA(cur ^ 1, 1, kt + 1);
    __builtin_amdgcn_s_barrier();
    asm volatile("s_waitcnt lgkmcnt(0)" ::: "memory");
    __builtin_amdgcn_s_setprio(1);
#pragma unroll
    for (int i = 2; i < 4; ++i)
#pragma unroll
      for (int j = 0; j < 2; ++j) {
        acc[i][j] = __builtin_amdgcn_mfma_f32_16x16x32_bf16(Af[i][0], Bf[j][0], acc[i][j], 0, 0, 0);
        acc[i][j] = __builtin_amdgcn_mfma_f32_16x16x32_bf16(Af[i][1], Bf[j][1], acc[i][j], 0, 0, 0);
      }
    __builtin_amdgcn_s_setprio(0);
    __builtin_amdgcn_s_barrier();

    // ---- phase 2: rows 0-3 x col 2 (no new ds_reads) ----
    if (kt + 2 < ksteps) stB(cur, kt + 2);
    __builtin_amdgcn_s_barrier();
    __builtin_amdgcn_s_setprio(1);
#pragma unroll
    for (int i = 0; i < 4; ++i) {
      acc[i][2] = __builtin_amdgcn_mfma_f32_16x16x32_bf16(Af[i][0], Bf[2][0], acc[i][2], 0, 0, 0);
      acc[i][2] = __builtin_amdgcn_mfma_f32_16x16x32_bf16(Af[i][1], Bf[2][1], acc[i][2], 0, 0, 0);
    }
    __builtin_amdgcn_s_setprio(0);
    if (kt < ksteps - 2) asm volatile("s_waitcnt vmcnt(3)" ::: "memory");
    else                 asm volatile("s_waitcnt vmcnt(0)" ::: "memory");
    __builtin_amdgcn_s_barrier();
  }

  // epilogue: C[16x16] frag layout col=lane&15, row=(lane>>4)*4+r
  const int rr = (lane >> 4) * 4;
  const int cc = lane & 15;
  if constexpr (!FUSE) {
#pragma unroll
    for (int i = 0; i < 4; ++i) {
      const int grow = m0 + wm + i * 16 + rr;
#pragma unroll
      for (int j = 0; j < 3; ++j) {
        const int gcol = n0 + wn + j * 16 + cc;
        CT* cp = Cg + (size_t)grow * NT + gcol;
#pragma unroll
        for (int r = 0; r < 4; ++r) storeC(acc[i][j][r], cp + (size_t)r * NT);
      }
    }
  } else {
    // layer-2 tail fused: z=0 -> out_mu (dropout only); z=1 -> out_sig
    const float inv_keep  = 1.f / 0.9f;
    const float inv_units = 1.f / 1152.f;
    float wcol[3];
    if (which) {
#pragma unroll
      for (int j = 0; j < 3; ++j) wcol[j] = ws2[n0 + wn + j * 16 + cc];
    }
#pragma unroll
    for (int i = 0; i < 4; ++i) {
#pragma unroll
      for (int r = 0; r < 4; ++r) {
        const int grow = m0 + wm + i * 16 + rr + r;
        const float rterm = which ? (r2mu[grow] + r2sg[grow]) : 0.f;
#pragma unroll
        for (int j = 0; j < 3; ++j) {
          const int gcol = n0 + wn + j * 16 + cc;
          const float mm = (float)mask2[(size_t)grow * NT + gcol];
          const float v = acc[i][j][r];
          float o;
          if (which == 0) {
            o = v * mm * inv_keep;
          } else {
            float sig4 = cleanf(v + rterm * wcol[j]);
            o = cleanf(cleanf(sig4 * mm * inv_units));
          }
          Cg[(size_t)grow * NT + gcol] = (CT)o;
        }
      }
    }
  }
}

// ---------------------------------------------------------------------------
// mid: layer-1 epilogue: sigma assembly, GELU moments, dropout;
// emits A2 bf16 + As2 bf16; row sums for layer-2 Sigma terms.
// ---------------------------------------------------------------------------
__global__ __launch_bounds__(256) void mid_kernel(
    const unsigned short* __restrict__ mu1, const unsigned short* __restrict__ S1,
    const int* __restrict__ mask1, const float* __restrict__ ws1,
    const float* __restrict__ rmu2, const float* __restrict__ rsg,
    unsigned short* __restrict__ A2, unsigned short* __restrict__ As2,
    float* __restrict__ r2mu, float* __restrict__ r2sg)
{
  const int row = blockIdx.x;
  const int tid = threadIdx.x;
  const float rterm = rmu2[row] + rsg[row];
  const ushort4* mup = (const ushort4*)(mu1 + (size_t)row * N1);
  const ushort4* s1p = (const ushort4*)(S1 + (size_t)row * N1);
  const int4* mkp = (const int4*)(mask1 + (size_t)row * N1);
  const float4* wsp = (const float4*)ws1;
  ushort4* a2p = (ushort4*)(A2 + (size_t)row * N1);
  ushort4* as2p = (ushort4*)(As2 + (size_t)row * N1);
  float smu = 0.f, ssg = 0.f;
  for (int j = tid; j < N1 / 4; j += 256) {
    ushort4 m4 = mup[j]; ushort4 s4 = s1p[j]; int4 k4 = mkp[j]; float4 w4 = wsp[j];
    float xv[4] = {bf2f(m4.x), bf2f(m4.y), bf2f(m4.z), bf2f(m4.w)};
    float Sv[4] = {bf2f(s4.x), bf2f(s4.y), bf2f(s4.z), bf2f(s4.w)};
    float wv[4] = {w4.x, w4.y, w4.z, w4.w};
    int   kv[4] = {k4.x, k4.y, k4.z, k4.w};
    unsigned short oa[4], os[4];
#pragma unroll
    for (int t = 0; t < 4; t++) {
      float sig1 = cleanf(Sv[t] + rterm * wv[t]);
      float x = xv[t];
      float cdf = 0.5f * (1.f + erff(x * 0.70710678118654752f));
      float pdf = expf(-0.5f * x * x) * 0.3989422804014327f;
      float g = cdf + x * pdf;
      float mu2v = x * cdf;
      float sig2 = g * g * sig1;
      float mm = (float)kv[t];
      float mu3 = mu2v * mm * (1.f / 0.9f);
      float sig3 = cleanf(sig2 * mm * (1.f / 4608.f));
      smu += mu3 * mu3;
      ssg += sig3;
      oa[t] = f2bf(mu3);
      os[t] = f2bf(sig3);
    }
    a2p[j] = make_ushort4(oa[0], oa[1], oa[2], oa[3]);
    as2p[j] = make_ushort4(os[0], os[1], os[2], os[3]);
  }
  __shared__ float red[2][4];
  for (int off = 32; off; off >>= 1) {
    smu += __shfl_down(smu, off);
    ssg += __shfl_down(ssg, off);
  }
  const int lane = tid & 63, wv2 = tid >> 6;
  if (!lane) { red[0][wv2] = smu; red[1][wv2] = ssg; }
  __syncthreads();
  if (tid == 0) {
    r2mu[row] = red[0][0] + red[0][1] + red[0][2] + red[0][3];
    r2sg[row] = red[1][0] + red[1][1] + red[1][2] + red[1][3];
  }
}

// ---------------------------------------------------------------------------
extern "C" void kernel_launch(void* const* d_in, const int* in_sizes, int n_in,
                              void* d_out, int out_size, void* d_ws, size_t ws_size,
                              hipStream_t stream)
{
  const float* mu_in = (const float*)d_in[0];
  const float* sg_in = (const float*)d_in[1];
  const int* mask1 = (const int*)d_in[2];
  const int* mask2 = (const int*)d_in[3];
  const float* w_mu1 = (const float*)d_in[4];
  const float* wsig1 = (const float*)d_in[5];
  const float* w_mu2 = (const float*)d_in[6];
  const float* wsig2 = (const float*)d_in[7];
  float* out = (float*)d_out;

  char* ws = (char*)d_ws;
  // Fixed layout with explicit overlays (bytes):
  const size_t oA1  = 0;                           // 37,748,736  A1 / A2 (bf16)
  const size_t oAs  = oA1  + (size_t)37748736;     // As16 (L1/L2 sigma, bf16)
  const size_t oB1t = oAs  + (size_t)37748736;     // 42,467,328  B1t
  const size_t oB1q = oB1t + (size_t)42467328;     // B1sq16
  const size_t oB2t = oB1q + (size_t)42467328;     // 10,616,832
  const size_t oB2q = oB2t + (size_t)10616832;     // B2sq16
  const size_t oMu1 = oB2q + (size_t)10616832;     // 37,748,736  mu1b
  const size_t oS1  = oMu1 + (size_t)37748736;     // S1b16
  const size_t oVec = oS1  + (size_t)37748736;

  unsigned short* A1     = (unsigned short*)(ws + oA1);
  unsigned short* As16   = (unsigned short*)(ws + oAs);   // sigma activations (bf16)
  unsigned short* B1t    = (unsigned short*)(ws + oB1t);
  unsigned short* B1sq16 = (unsigned short*)(ws + oB1q);
  unsigned short* B2t    = (unsigned short*)(ws + oB2t);
  unsigned short* B2sq16 = (unsigned short*)(ws + oB2q);
  unsigned short* mu1b   = (unsigned short*)(ws + oMu1);
  unsigned short* S1b16  = (unsigned short*)(ws + oS1);

  float* rmu2 = (float*)(ws + oVec);
  float* rsg  = rmu2 + Mrows;
  float* r2mu = rsg + Mrows;
  float* r2sg = r2mu + Mrows;
  float* ws1v = r2sg + Mrows;
  float* ws2v = ws1v + N1;
  float* part1 = ws2v + N2;            // NPART1 floats
  float* part2 = part1 + NPART1;       // NPART2 floats

  prep_in<<<Mrows, 256, 0, stream>>>(mu_in, sg_in, A1, As16, rmu2, rsg);
  prep_w2x<<<dim3(K1 / 64, N1 / 64 + N2 / 64), 256, 0, stream>>>(
      w_mu1, w_mu2, B1t, B1sq16, B2t, B2sq16, part1, part2);
  kl_prep<<<1, 256, 0, stream>>>(wsig1, wsig2, part1, part2, ws1v, ws2v,
                                 out + (size_t)2 * Mrows * N2);

  // layer 1: mu + sigma z-packed; 24 x 32 x 2 = 1536 = 3 x 512 slots (2/CU)
  gemm256<N1, unsigned short, false><<<dim3(N1 / 192, Mrows / 128, 2), 512, 0, stream>>>(
      A1, As16, B1t, B1sq16, mu1b, S1b16, nullptr, nullptr, nullptr, nullptr);

  mid_kernel<<<Mrows, 256, 0, stream>>>(mu1b, S1b16, mask1, ws1v, rmu2, rsg,
                                        A1, As16, r2mu, r2sg);

  // layer 2: NT=1152, fused final epilogue; 6 x 32 x 2 = 384 blocks (<=512)
  gemm256<N2, float, true><<<dim3(N2 / 192, Mrows / 128, 2), 512, 0, stream>>>(
      A1, As16, B2t, B2sq16, out, out + (size_t)Mrows * N2,
      mask2, ws2v, r2mu, r2sg);

  (void)in_sizes; (void)n_in; (void)out_size; (void)ws_size;
}